// Round 3
// baseline (1304.963 us; speedup 1.0000x reference)
//
#include <hip/hip_runtime.h>

// LSTMModel: 4-layer LSTM (H=50, IN=7, B=1024, T=512) + FC(50->25 relu ->1).
// R11: wave-per-layer recurrence. R8/R10's 16-wave M-partitioned structure puts
// the per-timestep barrier inside the h(t)->h(t+1) path (h distributed over 4
// waves) and stacks ds_read-burst + MFMA-chain + transcendental-chain latency
// into a 2090cy tick that no pipe-throughput edit can shrink (R10: -100cy VALU
// -> -17cy tick). Here ONE wave owns a whole layer (M=208 rows = 13 chunks,
// all 4 batches): own-h feedback is intra-wave (LDS write -> lgkmcnt -> read,
// no barrier dependency), and a second wave per layer computes the input-half
// pre(t) = Wih*h_below(t)+b one step ahead (skew 2 steps/layer, 519 steps).
// 8 waves (512 thr): SIMD l hosts rec-l + input-l. Weights live in a SINGLE
// register array af[13][2] (role-dependent content: Whh for rec, Wih+bias for
// input) so both paths share the allocation. Gate extraction from the 13 accs
// is a static cndmask select tree (cc = 4j+tsel; no runtime reg indexing).
// Schedule: rec-l at step s does t = s-2l-1 (reads pre[lay][s&1] written by
// input-l at s-1; reads own h(t-1) slot (t-1)&7 written by itself at s-1;
// input-l at s does t' = s-2l reading h_{l-1}(t') written by rec-(l-1) at s-1).
// All cross-wave reads target previous-step writes -> one barrier per step.
// exp2 gate constants folded into weights+bias (R10). pre is f32 (exact).

#define H 50
#define INSZ 7
#define TT 512
#define NL 4
#define FC1N 25
#define BPG 4
#define NBLK 256
#define NTHREADS 512
#define NCH 13        // M-chunks of 16 gate-rows (208 >= 200)
#define HRS 80        // hring row stride in halves (2-way banks: free)
#define PRS 216       // pre row stride in floats (24 mod 32: 2-way banks)
#define XD 32         // x ring depth
#define XW 32         // x row width in halves (k 8..31 stay zero)

typedef _Float16 half_t;
typedef __attribute__((ext_vector_type(8))) _Float16 half8_t;
typedef __attribute__((ext_vector_type(4))) float float4_t;

struct Params {
  const float* x;
  const float* Wih[NL];
  const float* Whh[NL];
  const float* bih[NL];
  const float* bhh[NL];
  const float* W1;
  const float* b1;
  const float* W2;
  const float* b2;
  float* out;
};

#define MFMA16(A, B, C) __builtin_amdgcn_mfma_f32_16x16x32_f16((A), (B), (C), 0, 0, 0)
#define EXP2F(x) __builtin_amdgcn_exp2f(x)
#define RCPF(x) __builtin_amdgcn_rcpf(x)

// Full gate update for one (unit,batch): g = pre-scaled gate pre-acts
// (i,f,g,o); c = cell state (in/out); h = new hidden (declared by macro).
#define UPD(g, c, h)                                                     \
  const float di = 1.0f + EXP2F((g)[0]);                                 \
  const float df = 1.0f + EXP2F((g)[1]);                                 \
  const float dgg = 1.0f + EXP2F((g)[2]);                                \
  const float dq = 1.0f + EXP2F((g)[3]);                                 \
  const float r1 = RCPF(di * df);                                        \
  const float r2 = RCPF(dgg * dq);                                       \
  const float gi = r1 * df;                                              \
  const float gf = r1 * di;                                              \
  const float gg = 2.0f * (r2 * dq) - 1.0f;                              \
  const float go = r2 * dgg;                                             \
  (c) = gf * (c) + gi * gg;                                              \
  const float dc = 1.0f + EXP2F(-2.885390082f * (c));                    \
  const float h = go * (2.0f * RCPF(dc) - 1.0f);

__global__ __launch_bounds__(NTHREADS, 2) void lstm_r11(Params p) {
  __shared__ __align__(16) half_t hring[NL][8][BPG][HRS];  // h_l(t) ring; 1.0@H
  __shared__ __align__(16) half_t xring[XD][BPG][XW];      // x(t) ring; 1.0@7
  __shared__ __align__(16) float preb[NL][2][BPG][PRS];    // pre, dbuf by parity
  __shared__ float fc1_buf[BPG][FC1N];

  const int tid = threadIdx.x;
  const int b0 = blockIdx.x * BPG;
  const int lane = tid & 63;
  const int quad = lane >> 4;
  const int col = lane & 15;
  const int w = tid >> 6;        // 0..7
  const bool isrec = (w < 4);    // waves 0..3: recurrence; 4..7: input GEMM
  const int lay = w & 3;
  const int bb = col & 3;
  const int tsel = col >> 2;

  // ---- A fragments: chunk cc covers gate-rows r = cc*16 + (lane&15);
  //      unit-major r = 4u+q -> u = cc*4 + tsel, q = col&3; k = kg*32+quad*8+j.
  //      rec: Whh (k<50).  input l==0: Wih0 k<7, bias k==7 (kg0 only).
  //      input l>=1: Wih k<50, bias k==50.  All pre-scaled by the gate's exp2
  //      constant (q==2 -> -2.885390082, else -1.442695041).
  half8_t af[NCH][2];
  {
    const int q = col & 3;
#pragma unroll
    for (int cc = 0; cc < NCH; ++cc) {
      const int u = cc * 4 + tsel;
#pragma unroll
      for (int kg = 0; kg < 2; ++kg) {
        half8_t v;
#pragma unroll
        for (int j = 0; j < 8; ++j) {
          const int k = kg * 32 + quad * 8 + j;
          float wv = 0.0f;
          if (u < H) {
            const int row = q * H + u;
            if (isrec) {
              if (k < H) wv = p.Whh[lay][row * H + k];
            } else if (lay == 0) {
              if (k < INSZ) wv = p.Wih[0][row * INSZ + k];
              else if (k == INSZ) wv = p.bih[0][row] + p.bhh[0][row];
            } else {
              if (k < H) wv = p.Wih[lay][row * H + k];
              else if (k == H) wv = p.bih[lay][row] + p.bhh[lay][row];
            }
            wv *= (q == 2) ? -2.885390082f : -1.442695041f;
          }
          v[j] = (half_t)wv;
        }
        af[cc][kg] = v;
      }
    }
  }

  // ---- init LDS ----
  {
    unsigned* hz = (unsigned*)hring;
    for (int i = tid; i < (int)(NL * 8 * BPG * HRS / 2); i += NTHREADS) hz[i] = 0u;
    unsigned* xz = (unsigned*)xring;
    for (int i = tid; i < (int)(XD * BPG * XW / 2); i += NTHREADS) xz[i] = 0u;
  }
  __syncthreads();
  // bias-1.0 slots
  for (int i = tid; i < NL * 8 * BPG; i += NTHREADS) {
    const int l = i >> 5, sl = (i >> 2) & 7, b = i & 3;
    hring[l][sl][b][H] = (half_t)1.0f;
  }
  for (int i = tid; i < XD * BPG; i += NTHREADS) {
    xring[i >> 2][i & 3][INSZ] = (half_t)1.0f;
  }
  // x prefill t = 0..31
  for (int i = tid; i < XD * BPG * INSZ; i += NTHREADS) {
    const int t = i / (BPG * INSZ), rem = i % (BPG * INSZ);
    const int b = rem / INSZ, k = rem % INSZ;
    xring[t][b][k] = (half_t)p.x[((size_t)(b0 + b) * TT + t) * INSZ + k];
  }
  __syncthreads();

  float csts[4] = {0.0f, 0.0f, 0.0f, 0.0f};
  const float4_t fz = {0.0f, 0.0f, 0.0f, 0.0f};

  const int NSTEP = TT + 2 * NL - 1;  // 519: s = 0..518
  for (int s = 0; s < NSTEP; ++s) {
    if (isrec) {
      const int t = s - 2 * lay - 1;
      if ((unsigned)t < TT) {
        float4_t acc[NCH];
        // own h(t-1): written by this same wave at step s-1 (or zeros at t=0)
        const half_t* hb = &hring[lay][(t - 1) & 7][bb][quad * 8];
        const half8_t v0 = *(const half8_t*)(hb);
        const half8_t v1 = *(const half8_t*)(hb + 32);
        // C-init = pre(t), written by input-lay at step s-1
        const float* pp = &preb[lay][s & 1][bb][quad * 4];
#pragma unroll
        for (int cc = 0; cc < NCH; ++cc)
          acc[cc] = *(const float4_t*)(pp + cc * 16);
#pragma unroll
        for (int cc = 0; cc < NCH; ++cc) acc[cc] = MFMA16(af[cc][0], v0, acc[cc]);
#pragma unroll
        for (int cc = 0; cc < NCH; ++cc) acc[cc] = MFMA16(af[cc][1], v1, acc[cc]);
        // extract + update + write h(t). Lane owns cc = 4j+tsel -> unit
        // u = 4*tsel + 16*j + quad (j<=2 always < 50; j==3 only tsel==0).
        half_t* hw = &hring[lay][t & 7][bb][0];
#pragma unroll
        for (int j = 0; j < 3; ++j) {
          const float4_t va = (tsel & 1) ? acc[4 * j + 1] : acc[4 * j + 0];
          const float4_t vb = (tsel & 1) ? acc[4 * j + 3] : acc[4 * j + 2];
          const float4_t ga = (tsel & 2) ? vb : va;
          UPD(ga, csts[j], h)
          hw[4 * tsel + 16 * j + quad] = (half_t)h;
        }
        {
          const float4_t ga = acc[12];
          UPD(ga, csts[3], h)
          if (tsel == 0 && quad < 2) hw[48 + quad] = (half_t)h;
        }
      }
    } else {
      const int t2 = s - 2 * lay;
      if ((unsigned)t2 < TT) {
        // x ring refill (input-0 wave): every 16 steps load t in [s+16, s+32)
        if (lay == 0 && (s & 15) == 0 && s + 16 < TT) {
          const int t0 = s + 16 + (lane >> 2);
          const int rb = lane & 3;
          if (t0 < TT) {
            const float* src = &p.x[((size_t)(b0 + rb) * TT + t0) * INSZ];
            half_t* dst = &xring[t0 & 31][rb][0];
#pragma unroll
            for (int k = 0; k < INSZ; ++k) dst[k] = (half_t)src[k];
          }
        }
        float4_t acc[NCH];
        const half_t* hb = (lay == 0)
                               ? &xring[t2 & 31][bb][quad * 8]
                               : &hring[lay - 1][t2 & 7][bb][quad * 8];
        const half8_t v0 = *(const half8_t*)(hb);
#pragma unroll
        for (int cc = 0; cc < NCH; ++cc) acc[cc] = MFMA16(af[cc][0], v0, fz);
        if (lay != 0) {
          const half8_t v1 = *(const half8_t*)(hb + 32);
#pragma unroll
          for (int cc = 0; cc < NCH; ++cc)
            acc[cc] = MFMA16(af[cc][1], v1, acc[cc]);
        }
        // write pre(t2) f32 into parity (s+1)&1; rep 0 lanes only
        if (tsel == 0) {
          float* pw = &preb[lay][(s + 1) & 1][bb][quad * 4];
#pragma unroll
          for (int cc = 0; cc < NCH; ++cc)
            *(float4_t*)(pw + cc * 16) = acc[cc];
        }
      }
    }
    __syncthreads();
  }

  // ---- FC head (fp32); h_3(511) is in hring[3][511&7] ----
  if (tid < BPG * FC1N) {
    const int b = tid / FC1N, j = tid % FC1N;
    const float* wgt = p.W1 + j * H;
    float a = p.b1[j];
#pragma unroll
    for (int k = 0; k < H; ++k)
      a += (float)hring[3][(TT - 1) & 7][b][k] * wgt[k];
    fc1_buf[b][j] = fmaxf(a, 0.0f);
  }
  __syncthreads();
  if (tid < BPG) {
    float a = p.b2[0];
#pragma unroll
    for (int j = 0; j < FC1N; ++j) a += fc1_buf[tid][j] * p.W2[j];
    p.out[b0 + tid] = a;
  }
}

extern "C" void kernel_launch(void* const* d_in, const int* in_sizes, int n_in,
                              void* d_out, int out_size, void* d_ws, size_t ws_size,
                              hipStream_t stream) {
  Params p;
  p.x = (const float*)d_in[0];
  for (int l = 0; l < NL; ++l) {
    p.Wih[l] = (const float*)d_in[1 + 4 * l];
    p.Whh[l] = (const float*)d_in[2 + 4 * l];
    p.bih[l] = (const float*)d_in[3 + 4 * l];
    p.bhh[l] = (const float*)d_in[4 + 4 * l];
  }
  p.W1 = (const float*)d_in[17];
  p.b1 = (const float*)d_in[18];
  p.W2 = (const float*)d_in[19];
  p.b2 = (const float*)d_in[20];
  p.out = (float*)d_out;

  hipLaunchKernelGGL(lstm_r11, dim3(NBLK), dim3(NTHREADS), 0, stream, p);
}

// Round 4
// 656.431 us; speedup vs baseline: 1.9880x; 1.9880x over previous
//
#include <hip/hip_runtime.h>

// LSTMModel: 4-layer LSTM (H=50, IN=7, B=1024, T=512) + FC(50->25 relu ->1).
// R12 = R11's wave-owns-layer dataflow with the register pressure HALVED.
//
// R11 post-mortem: WRITE_SIZE 20MB -> 1.15GB (scratch spill flushes, ~16B per
// thread per step), VGPR_Count 116 at a 128 cap while demand was ~190
// (af[13][2]=104 + acc[13]=52 + temps). The dataflow was correct (passed,
// absmax unchanged); the spill was the whole 1305us.
// Fix insight: the per-step __syncthreads() means h(t-1) written at step s-1
// is visible to ANY wave at step s -- "intra-wave recurrence" was never
// load-bearing. So split each layer across TWO rec waves (7+6 chunks of 16
// gate-rows) and TWO input waves: af[7][2]=56 VGPR, acc[7]=28, total ~115
// < 128 cap (launch_bounds(1024,4): 16 waves/block, 4 waves/SIMD, 1 blk/CU).
//
// Schedule (unchanged from R11): step s, one barrier per step, 519 steps.
//   rec-l   does t  = s-2l-1: C-init from preb[l][s&1] (written s-1 by
//           input-l), + Whh * h_l(t-1) (hring slot (t-1)&7, written s-1),
//           gate update, h -> hring slot t&7.
//   input-l does t' = s-2l:   pre(t') = Wih*h_{l-1}(t') [+bias] -> f32
//           preb[l][(s+1)&1]. L0 reads the x ring instead.
// exp2 gate constants folded into weights+bias (R10). pre kept f32 (exact).
// C/D layout: acc[lcc][i] = gate i of unit u=(cb0+lcc)*4+quad, batch col&3;
// lane updates chunks lcc=tsel and lcc=4+tsel via a static cndmask tree
// (2 UPDs/lane max, no runtime register indexing).

#define H 50
#define INSZ 7
#define TT 512
#define NL 4
#define FC1N 25
#define BPG 4
#define NBLK 256
#define NTHREADS 1024
#define HRS 80        // hring row stride in halves
#define PRS 216       // pre row stride in floats
#define XD 32         // x ring depth
#define XW 32         // x row width in halves (k 8..31 stay zero)

typedef _Float16 half_t;
typedef __attribute__((ext_vector_type(8))) _Float16 half8_t;
typedef __attribute__((ext_vector_type(4))) float float4_t;

struct Params {
  const float* x;
  const float* Wih[NL];
  const float* Whh[NL];
  const float* bih[NL];
  const float* bhh[NL];
  const float* W1;
  const float* b1;
  const float* W2;
  const float* b2;
  float* out;
};

#define MFMA16(A, B, C) __builtin_amdgcn_mfma_f32_16x16x32_f16((A), (B), (C), 0, 0, 0)
#define EXP2F(x) __builtin_amdgcn_exp2f(x)
#define RCPF(x) __builtin_amdgcn_rcpf(x)

// Gate update: g = pre-scaled (i,f,g,o) pre-acts; c = cell (in/out); h = out.
#define UPD(g, c, h)                                                     \
  const float di = 1.0f + EXP2F((g)[0]);                                 \
  const float df = 1.0f + EXP2F((g)[1]);                                 \
  const float dgg = 1.0f + EXP2F((g)[2]);                                \
  const float dq = 1.0f + EXP2F((g)[3]);                                 \
  const float r1 = RCPF(di * df);                                        \
  const float r2 = RCPF(dgg * dq);                                       \
  const float gi = r1 * df;                                              \
  const float gf = r1 * di;                                              \
  const float gg = 2.0f * (r2 * dq) - 1.0f;                              \
  const float go = r2 * dgg;                                             \
  (c) = gf * (c) + gi * gg;                                              \
  const float dc = 1.0f + EXP2F(-2.885390082f * (c));                    \
  const float h = go * (2.0f * RCPF(dc) - 1.0f);

__global__ __launch_bounds__(NTHREADS, 4) void lstm_r12(Params p) {
  __shared__ __align__(16) half_t hring[NL][8][BPG][HRS];  // h_l(t) ring; 1.0@H
  __shared__ __align__(16) half_t xring[XD][BPG][XW];      // x(t) ring; 1.0@7
  __shared__ __align__(16) float preb[NL][2][BPG][PRS];    // pre, dbuf by parity
  __shared__ float fc1_buf[BPG][FC1N];

  const int tid = threadIdx.x;
  const int b0 = blockIdx.x * BPG;
  const int lane = tid & 63;
  const int quad = lane >> 4;
  const int col = lane & 15;
  const int w = tid >> 6;        // 0..15
  const bool isrec = (w < 8);    // 0..7: recurrence halves; 8..15: input halves
  const int sub = w & 7;
  const int lay = sub >> 1;
  const int hf = sub & 1;        // which half of the 13 chunks
  const int cb0 = hf * 7;        // global chunk base (0 or 7)
  const int nch = 7 - hf;        // local chunks: 7 (hf0) or 6 (hf1)
  const int bb = col & 3;
  const int tsel = col >> 2;

  // ---- A fragments: local chunk lcc -> global cc=cb0+lcc covers gate-rows
  //      r = cc*16 + (lane&15); r=4u+q -> u = cc*4+tsel, q = col&3;
  //      k = kg*32 + quad*8 + j. rec: Whh (k<50). input l==0: Wih0 k<7,
  //      bias k==7. input l>=1: Wih k<50, bias k==50. Pre-scaled by the
  //      gate's exp2 constant (q==2 -> -2.885390082, else -1.442695041).
  half8_t af[7][2];
  {
    const int q = col & 3;
#pragma unroll
    for (int lcc = 0; lcc < 7; ++lcc) {
      const int u = (cb0 + lcc) * 4 + tsel;
#pragma unroll
      for (int kg = 0; kg < 2; ++kg) {
        half8_t v;
#pragma unroll
        for (int j = 0; j < 8; ++j) {
          const int k = kg * 32 + quad * 8 + j;
          float wv = 0.0f;
          if (u < H) {
            const int row = q * H + u;
            if (isrec) {
              if (k < H) wv = p.Whh[lay][row * H + k];
            } else if (lay == 0) {
              if (k < INSZ) wv = p.Wih[0][row * INSZ + k];
              else if (k == INSZ) wv = p.bih[0][row] + p.bhh[0][row];
            } else {
              if (k < H) wv = p.Wih[lay][row * H + k];
              else if (k == H) wv = p.bih[lay][row] + p.bhh[lay][row];
            }
            wv *= (q == 2) ? -2.885390082f : -1.442695041f;
          }
          v[j] = (half_t)wv;
        }
        af[lcc][kg] = v;
      }
    }
  }

  // ---- init LDS ----
  {
    unsigned* hz = (unsigned*)hring;
    for (int i = tid; i < (int)(NL * 8 * BPG * HRS / 2); i += NTHREADS) hz[i] = 0u;
    unsigned* xz = (unsigned*)xring;
    for (int i = tid; i < (int)(XD * BPG * XW / 2); i += NTHREADS) xz[i] = 0u;
  }
  __syncthreads();
  if (tid < NL * 8 * BPG) {  // hring bias-1.0 at slot H (all ring slots)
    const int l = tid >> 5, sl = (tid >> 2) & 7, b = tid & 3;
    hring[l][sl][b][H] = (half_t)1.0f;
  } else if (tid < NL * 8 * BPG + XD * BPG) {  // xring bias-1.0 at slot 7
    const int i = tid - NL * 8 * BPG;
    xring[i >> 2][i & 3][INSZ] = (half_t)1.0f;
  }
  // x prefill t = 0..31
  for (int i = tid; i < XD * BPG * INSZ; i += NTHREADS) {
    const int t = i / (BPG * INSZ), rem = i % (BPG * INSZ);
    const int b = rem / INSZ, k = rem % INSZ;
    xring[t][b][k] = (half_t)p.x[((size_t)(b0 + b) * TT + t) * INSZ + k];
  }
  __syncthreads();

  float cst0 = 0.0f, cst1 = 0.0f;
  const float4_t fz = {0.0f, 0.0f, 0.0f, 0.0f};

  const int NSTEP = TT + 2 * NL - 1;  // 519
  for (int s = 0; s < NSTEP; ++s) {
    if (isrec) {
      const int t = s - 2 * lay - 1;
      if ((unsigned)t < TT) {
        const half_t* hb = &hring[lay][(t - 1) & 7][bb][quad * 8];
        const half8_t v0 = *(const half8_t*)(hb);
        const half8_t v1 = *(const half8_t*)(hb + 32);
        const float* pp = &preb[lay][s & 1][bb][quad * 4];
        float4_t acc[7];
#pragma unroll
        for (int lcc = 0; lcc < 6; ++lcc)
          acc[lcc] = *(const float4_t*)(pp + (cb0 + lcc) * 16);
        acc[6] = (nch == 7) ? *(const float4_t*)(pp + (cb0 + 6) * 16) : fz;
#pragma unroll
        for (int lcc = 0; lcc < 6; ++lcc)
          acc[lcc] = MFMA16(af[lcc][0], v0, acc[lcc]);
        if (nch == 7) acc[6] = MFMA16(af[6][0], v0, acc[6]);
#pragma unroll
        for (int lcc = 0; lcc < 6; ++lcc)
          acc[lcc] = MFMA16(af[lcc][1], v1, acc[lcc]);
        if (nch == 7) acc[6] = MFMA16(af[6][1], v1, acc[6]);
        // extract owned chunks lcc0=tsel, lcc1=4+tsel (static cndmask tree)
        const float4_t x01 = (tsel & 1) ? acc[1] : acc[0];
        const float4_t x23 = (tsel & 1) ? acc[3] : acc[2];
        const float4_t o0 = (tsel & 2) ? x23 : x01;
        const float4_t y45 = (tsel & 1) ? acc[5] : acc[4];
        const float4_t o1 = (tsel & 2) ? acc[6] : y45;
        half_t* hw = &hring[lay][t & 7][bb][0];
        {
          UPD(o0, cst0, h0v)
          hw[(cb0 + tsel) * 4 + quad] = (half_t)h0v;  // u0 always valid
        }
        {
          UPD(o1, cst1, h1v)
          const int u1 = (cb0 + 4 + tsel) * 4 + quad;
          if ((4 + tsel) < nch && u1 < H) hw[u1] = (half_t)h1v;
        }
      }
    } else {
      const int t2 = s - 2 * lay;
      if ((unsigned)t2 < TT) {
        // x ring refill: input-L0-hf1 wave (w==9), every 16 steps
        if (w == 9 && (s & 15) == 0 && s + 16 < TT) {
          const int t0 = s + 16 + (lane >> 2);
          const int rb = lane & 3;
          const float* src = &p.x[((size_t)(b0 + rb) * TT + t0) * INSZ];
          half_t* dst = &xring[t0 & 31][rb][0];
#pragma unroll
          for (int k = 0; k < INSZ; ++k) dst[k] = (half_t)src[k];
        }
        const half_t* hb = (lay == 0)
                               ? &xring[t2 & 31][bb][quad * 8]
                               : &hring[lay - 1][t2 & 7][bb][quad * 8];
        const half8_t v0 = *(const half8_t*)(hb);
        float4_t acc[7];
#pragma unroll
        for (int lcc = 0; lcc < 6; ++lcc) acc[lcc] = MFMA16(af[lcc][0], v0, fz);
        acc[6] = (nch == 7) ? MFMA16(af[6][0], v0, fz) : fz;
        if (lay != 0) {
          const half8_t v1 = *(const half8_t*)(hb + 32);
#pragma unroll
          for (int lcc = 0; lcc < 6; ++lcc)
            acc[lcc] = MFMA16(af[lcc][1], v1, acc[lcc]);
          if (nch == 7) acc[6] = MFMA16(af[6][1], v1, acc[6]);
        }
        if (tsel == 0) {  // one replica writes pre (f32, by gate-row r)
          float* pw = &preb[lay][(s + 1) & 1][bb][quad * 4];
#pragma unroll
          for (int lcc = 0; lcc < 6; ++lcc)
            *(float4_t*)(pw + (cb0 + lcc) * 16) = acc[lcc];
          if (nch == 7) *(float4_t*)(pw + (cb0 + 6) * 16) = acc[6];
        }
      }
    }
    __syncthreads();
  }

  // ---- FC head (fp32); h_3(511) is in hring[3][(TT-1)&7] ----
  if (tid < BPG * FC1N) {
    const int b = tid / FC1N, j = tid % FC1N;
    const float* wgt = p.W1 + j * H;
    float a = p.b1[j];
#pragma unroll
    for (int k = 0; k < H; ++k)
      a += (float)hring[3][(TT - 1) & 7][b][k] * wgt[k];
    fc1_buf[b][j] = fmaxf(a, 0.0f);
  }
  __syncthreads();
  if (tid < BPG) {
    float a = p.b2[0];
#pragma unroll
    for (int j = 0; j < FC1N; ++j) a += fc1_buf[tid][j] * p.W2[j];
    p.out[b0 + tid] = a;
  }
}

extern "C" void kernel_launch(void* const* d_in, const int* in_sizes, int n_in,
                              void* d_out, int out_size, void* d_ws, size_t ws_size,
                              hipStream_t stream) {
  Params p;
  p.x = (const float*)d_in[0];
  for (int l = 0; l < NL; ++l) {
    p.Wih[l] = (const float*)d_in[1 + 4 * l];
    p.Whh[l] = (const float*)d_in[2 + 4 * l];
    p.bih[l] = (const float*)d_in[3 + 4 * l];
    p.bhh[l] = (const float*)d_in[4 + 4 * l];
  }
  p.W1 = (const float*)d_in[17];
  p.b1 = (const float*)d_in[18];
  p.W2 = (const float*)d_in[19];
  p.b2 = (const float*)d_in[20];
  p.out = (float*)d_out;

  hipLaunchKernelGGL(lstm_r12, dim3(NBLK), dim3(NTHREADS), 0, stream, p);
}

// Round 5
// 559.894 us; speedup vs baseline: 2.3307x; 1.1724x over previous
//
#include <hip/hip_runtime.h>

// LSTMModel: 4-layer LSTM (H=50, IN=7, B=1024, T=512) + FC(50->25 relu ->1).
// R13 = R10's dataflow with the per-tick __syncthreads() replaced by per-group
// LDS flag sync, so the 16 waves DE-PHASE.
//
// Why: counters across R8/R10/R12 show a consistent MfmaUtil ~3.7x above the
// issue-count prediction => one 16x16x32 MFMA occupies the matrix pipe
// ~16-18cy here, i.e. R8's tick = MFMA ~810cy + VALU ~1040cy + LDS ~700cy,
// summing to ~125% of the 2090cy tick: the pipes DON'T overlap because the
// global barrier phase-locks all waves (everyone reads, then everyone MFMAs,
// then everyone does trans math). R10 (-100cy VALU -> -17cy tick) and R9
// (within-wave reorder, slower) bracket this: only cross-wave de-phasing can
// compress the tick toward max(pipe) ~1000cy.
//
// Sync design: prod[4] counters in LDS, +1 per wave per tick (release).
// Group g entering tick T spins until:
//   own : prod[g]   >= 4T       (siblings finished T-1)
//   prev: prod[g-1] >= 4(T+1)   (h_{g-1}(T) fully stored)     [g>=1]
//   next: prod[g+1] >= 4(T-1)   (write-safety for parity reuse) [g<=2]
// All h buffers are TRIPLE-buffered (parity T%3) so the write-safety window
// above is sufficient (verified for every read/clobber pair). Groups then run
// T=0..511 with no slot guards; the pipeline skew emerges by itself, and each
// SIMD (one wave per group) holds 4 waves at 4 different phases.
// Release = s_waitcnt lgkmcnt(0) + lane0 ds_add; acquire = volatile spin +
// sched_barrier + memory clobber.
//
// Layout (R8/R10 unchanged except parity depth 3):
// XP[3][4][80]: row = [x(T) 0..6 | 1.0 at 7 | h0(T-1) 8..57]; g0 reads parity
//   (T-1)%3, writes h0(T)+x(T+1) into parity T%3; g1 reads parity T%3.
// Hb[l-1][3][4][80]: h_l, parity T%3 = tick written; const-1.0 at col 56.
// Xstage[32][4][8]: raw-x ring, refilled 16 ticks ahead by xwave AFTER its
//   counter bump (off the group-critical path).
// exp2 constants folded into weights/bias (R10); FC reads h3(511) from LDS.

#define H 50
#define INSZ 7
#define TT 512
#define NL 4
#define FC1N 25
#define BPG 4
#define NBLK 256
#define NTHREADS 1024
#define HS 80        // row stride in halves (40 dw = 8 mod 32: <=2-way, free)
#define BIASL 56

typedef _Float16 half_t;
typedef __attribute__((ext_vector_type(8))) _Float16 half8_t;
typedef __attribute__((ext_vector_type(4))) float float4_t;

struct Params {
  const float* x;
  const float* Wih[NL];
  const float* Whh[NL];
  const float* bih[NL];
  const float* bhh[NL];
  const float* W1;
  const float* b1;
  const float* W2;
  const float* b2;
  float* out;
};

#define MFMA16(A, B, C) __builtin_amdgcn_mfma_f32_16x16x32_f16((A), (B), (C), 0, 0, 0)
#define EXP2F(x) __builtin_amdgcn_exp2f(x)
#define RCPF(x) __builtin_amdgcn_rcpf(x)

__global__ __launch_bounds__(NTHREADS, 4) void lstm_r13(Params p) {
  __shared__ __align__(16) half_t XP[3][BPG][HS];        // L0 B-row / L1 input
  __shared__ __align__(16) half_t Hb[3][3][BPG][HS];     // h of L1..L3, 3-parity
  __shared__ __align__(16) half_t Xstage[32][BPG][8];    // raw-x ring
  __shared__ int prodc[16];                              // [0..3] used, padded
  __shared__ float fc1_buf[BPG][FC1N];

  const int tid = threadIdx.x;
  const int b0 = blockIdx.x * BPG;
  const int lane = tid & 63;
  const int quad = lane >> 4;
  const int col = lane & 15;
  const int glay = tid >> 8;                     // layer group (4 waves each)
  const int wl = (((tid >> 6) & 3) + glay) & 3;  // M-chunk, SIMD-balanced

  // ---- A fragments: row r = wl*64 + t4*16 + col (unit-major r=4u+q),
  //      k = g*32 + quad*8 + j; rows pre-scaled by the gate's exp2 constant.
  half8_t afrag[4][4];
#pragma unroll
  for (int t4 = 0; t4 < 4; ++t4) {
#pragma unroll
    for (int g = 0; g < 4; ++g) {
      half8_t v;
#pragma unroll
      for (int j = 0; j < 8; ++j) {
        const int r = wl * 64 + t4 * 16 + col;
        const int u = r >> 2, q = r & 3;
        const int k = g * 32 + quad * 8 + j;
        float wv = 0.0f;
        if (u < H) {
          const int row = q * H + u;
          if (glay == 0) {           // K=64: x 0..6, bias 7, own-h 8..57
            if (k < INSZ) wv = p.Wih[0][row * INSZ + k];
            else if (k == 7) wv = p.bih[0][row] + p.bhh[0][row];
            else if (k >= 8 && k < 8 + H) wv = p.Whh[0][row * H + (k - 8)];
          } else if (glay == 1) {    // input from XP: bias 7, in-h 8..57
            if (k == 7) wv = p.bih[1][row] + p.bhh[1][row];
            else if (k >= 8 && k < 8 + H) wv = p.Wih[1][row * H + (k - 8)];
            else if (k >= 64 && k < 64 + H) wv = p.Whh[1][row * H + (k - 64)];
          } else {                   // in-h 0..49, bias 56, own-h 64..113
            if (k < H) wv = p.Wih[glay][row * H + k];
            else if (k == BIASL) wv = p.bih[glay][row] + p.bhh[glay][row];
            else if (k >= 64 && k < 64 + H) wv = p.Whh[glay][row * H + (k - 64)];
          }
          wv *= (q == 2) ? -2.885390082f : -1.442695041f;  // fold exp2 scale
        }
        v[j] = (half_t)wv;
      }
      afrag[t4][g] = v;
    }
  }

  // ---- init LDS ----
  {
    unsigned* xz = (unsigned*)XP;
    for (int i = tid; i < 3 * BPG * HS / 2; i += NTHREADS) xz[i] = 0u;
    unsigned* hz = (unsigned*)Hb;
    for (int i = tid; i < 3 * 3 * BPG * HS / 2; i += NTHREADS) hz[i] = 0u;
    if (tid < 16) prodc[tid] = 0;
  }
  __syncthreads();
  if (tid < 12) {  // XP bias-1.0 at col 7, all 3 parities
    XP[tid >> 2][tid & 3][7] = (half_t)1.0f;
  } else if (tid < 12 + 36) {  // Hb const-1.0 at col 56, all parities
    const int i = tid - 12, l = i / 12, pr = (i >> 2) % 3, b = i & 3;
    Hb[l][pr][b][BIASL] = (half_t)1.0f;
  }
  // x prefill t = 0..31 + x(0) into XP[2] (parity (0-1)%3)
  for (int i = tid; i < 32 * BPG * INSZ; i += NTHREADS) {
    const int t = i / (BPG * INSZ), rem = i % (BPG * INSZ);
    const int b = rem / INSZ, k = rem % INSZ;
    const half_t xh = (half_t)p.x[((size_t)(b0 + b) * TT + t) * INSZ + k];
    Xstage[t][b][k] = xh;
    if (t == 0) XP[2][b][k] = xh;
  }
  __syncthreads();

  // ---- per-lane roles ----
  const int bb = col & 3;
  const int tsel = col >> 2;
  const int uu = 16 * wl + 4 * tsel + quad;
  const bool updact = (uu < H);

  // pointers per parity pp (literal-indexed only -> stays in registers)
  const half_t* pin3[3];
  const half_t* pown3[3];
  half_t* pst3[3];
#pragma unroll
  for (int pp = 0; pp < 3; ++pp) {
    if (glay == 0) {
      pin3[pp] = &XP[pp][bb][quad * 8];
      pown3[pp] = pin3[pp];  // unused
      pst3[pp] = &XP[pp][bb][8 + uu];
    } else if (glay == 1) {
      pin3[pp] = &XP[pp][bb][quad * 8];
      pown3[pp] = &Hb[0][pp][bb][quad * 8];
      pst3[pp] = &Hb[0][pp][bb][uu];
    } else {
      pin3[pp] = &Hb[glay - 2][pp][bb][quad * 8];
      pown3[pp] = &Hb[glay - 1][pp][bb][quad * 8];
      pst3[pp] = &Hb[glay - 1][pp][bb][uu];
    }
  }
  // effective input pointer for T%3 = 0,1,2: g0 reads parity (T-1)%3, others T%3
  const half_t* pinT[3] = {glay ? pin3[0] : pin3[2],
                           glay ? pin3[1] : pin3[0],
                           glay ? pin3[2] : pin3[1]};
  // own-h pointer: parity (T-1)%3
  const half_t* pownT[3] = {pown3[2], pown3[0], pown3[1]};

  // x-copy + ring-refill role: layer-0 wl==3 wave (lightest: 2 MFMAs)
  const bool xwave = (glay == 0) && (wl == 3);
  const bool xcopy = xwave && (lane < BPG * INSZ);
  const int cb = lane / INSZ, ck = lane % INSZ;  // valid when xcopy

  float cst = 0.0f;
  const float4_t fzc = {0.0f, 0.0f, 0.0f, 0.0f};
  volatile int* pv = (volatile int*)prodc;

  // ---- sync macros ----
#define WAITT(T_)                                                               \
  {                                                                             \
    const int bS = 4 * (T_);                                                    \
    if (glay == 0) {                                                            \
      while (pv[0] < bS || pv[1] < bS - 4) {}                                   \
    } else if (glay == 1) {                                                     \
      while (pv[1] < bS || pv[0] < bS + 4 || pv[2] < bS - 4) {}                 \
    } else if (glay == 2) {                                                     \
      while (pv[2] < bS || pv[1] < bS + 4 || pv[3] < bS - 4) {}                 \
    } else {                                                                    \
      while (pv[3] < bS || pv[2] < bS + 4) {}                                   \
    }                                                                           \
    __builtin_amdgcn_sched_barrier(0);                                          \
    asm volatile("" ::: "memory");                                              \
  }

#define DONE()                                                                  \
  {                                                                             \
    asm volatile("s_waitcnt lgkmcnt(0)" ::: "memory");                          \
    if (lane == 0) atomicAdd(&prodc[glay], 1);                                  \
  }

#define REFILL(T_)                                                              \
  if (xwave && ((T_)&15) == 0 && (T_) > 0 && (T_) + 16 < TT) {                  \
    const int t0 = (T_) + 16 + (lane >> 2);                                     \
    const int rb = lane & 3;                                                    \
    const float* src = &p.x[((size_t)(b0 + rb) * TT + t0) * INSZ];              \
    half_t* dst = &Xstage[t0 & 31][rb][0];                                      \
    _Pragma("unroll") for (int k = 0; k < INSZ; ++k) dst[k] = (half_t)src[k];   \
  }

  // ---- tick body: R10's TICK_BODY (no FCW; h3 read from LDS by FC head) ----
#define TICK3(PIN, POWN, PST)                                                   \
  {                                                                             \
    float4_t a0, a1, a2, a3;                                                    \
    if (glay == 0) {                                                            \
      const half8_t v0 = *(const half8_t*)(PIN);                                \
      const half8_t v1 = *(const half8_t*)((PIN) + 32);                         \
      __builtin_amdgcn_s_setprio(1);                                            \
      if (wl != 3) {                                                            \
        a0 = MFMA16(afrag[0][0], v0, fzc); a1 = MFMA16(afrag[1][0], v0, fzc);   \
        a2 = MFMA16(afrag[2][0], v0, fzc); a3 = MFMA16(afrag[3][0], v0, fzc);   \
        a0 = MFMA16(afrag[0][1], v1, a0); a1 = MFMA16(afrag[1][1], v1, a1);     \
        a2 = MFMA16(afrag[2][1], v1, a2); a3 = MFMA16(afrag[3][1], v1, a3);     \
      } else {                                                                  \
        a0 = MFMA16(afrag[0][0], v0, fzc);                                      \
        a0 = MFMA16(afrag[0][1], v1, a0);                                       \
        a1 = a0; a2 = a0; a3 = a0;                                              \
      }                                                                         \
      __builtin_amdgcn_s_setprio(0);                                            \
    } else {                                                                    \
      const half8_t v0 = *(const half8_t*)(PIN);                                \
      const half8_t v1 = *(const half8_t*)((PIN) + 32);                         \
      const half8_t v2 = *(const half8_t*)(POWN);                               \
      const half8_t v3 = *(const half8_t*)((POWN) + 32);                        \
      __builtin_amdgcn_s_setprio(1);                                            \
      if (wl != 3) {                                                            \
        a0 = MFMA16(afrag[0][0], v0, fzc); a1 = MFMA16(afrag[1][0], v0, fzc);   \
        a2 = MFMA16(afrag[2][0], v0, fzc); a3 = MFMA16(afrag[3][0], v0, fzc);   \
        a0 = MFMA16(afrag[0][1], v1, a0); a1 = MFMA16(afrag[1][1], v1, a1);     \
        a2 = MFMA16(afrag[2][1], v1, a2); a3 = MFMA16(afrag[3][1], v1, a3);     \
        a0 = MFMA16(afrag[0][2], v2, a0); a1 = MFMA16(afrag[1][2], v2, a1);     \
        a2 = MFMA16(afrag[2][2], v2, a2); a3 = MFMA16(afrag[3][2], v2, a3);     \
        a0 = MFMA16(afrag[0][3], v3, a0); a1 = MFMA16(afrag[1][3], v3, a1);     \
        a2 = MFMA16(afrag[2][3], v3, a2); a3 = MFMA16(afrag[3][3], v3, a3);     \
      } else {                                                                  \
        a0 = MFMA16(afrag[0][0], v0, fzc);                                      \
        a0 = MFMA16(afrag[0][1], v1, a0);                                       \
        a0 = MFMA16(afrag[0][2], v2, a0);                                       \
        a0 = MFMA16(afrag[0][3], v3, a0);                                       \
        a1 = a0; a2 = a0; a3 = a0;                                              \
      }                                                                         \
      __builtin_amdgcn_s_setprio(0);                                            \
    }                                                                           \
    if (updact) {                                                               \
      const float4_t g01 = (col & 4) ? a1 : a0;                                 \
      const float4_t g23 = (col & 4) ? a3 : a2;                                 \
      const float4_t ga = (col & 8) ? g23 : g01;                                \
      const float di = 1.0f + EXP2F(ga[0]);                                     \
      const float df = 1.0f + EXP2F(ga[1]);                                     \
      const float dg = 1.0f + EXP2F(ga[2]);                                     \
      const float dq = 1.0f + EXP2F(ga[3]);                                     \
      const float r1 = RCPF(di * df);                                           \
      const float r2 = RCPF(dg * dq);                                           \
      const float gi = r1 * df;                                                 \
      const float gf = r1 * di;                                                 \
      const float gg = 2.0f * (r2 * dq) - 1.0f;                                 \
      const float go = r2 * dg;                                                 \
      cst = gf * cst + gi * gg;                                                 \
      const float dc = 1.0f + EXP2F(-2.885390082f * cst);                       \
      const float h = go * (2.0f * RCPF(dc) - 1.0f);                            \
      *(PST) = (half_t)h;                                                       \
    }                                                                           \
  }

#define STEP(T_, P_)                                                            \
  {                                                                             \
    WAITT(T_)                                                                   \
    TICK3(pinT[P_], pownT[P_], pst3[P_])                                        \
    if (xcopy && (T_) + 1 < TT)                                                 \
      XP[P_][cb][ck] = Xstage[((T_) + 1) & 31][cb][ck];                         \
    DONE()                                                                      \
    REFILL(T_)                                                                  \
  }

  // ---- free-running tick loop: T = 0..511, triple-unrolled for parity ----
  for (int T = 0; T < 510; T += 3) {
    STEP(T, 0)
    STEP(T + 1, 1)
    STEP(T + 2, 2)
  }
  STEP(510, 0)
  STEP(511, 1)
  __syncthreads();

  // ---- FC head (fp32); h3(511) is in Hb[2][511%3=1] cols 0..49 ----
  if (tid < BPG * FC1N) {
    const int b = tid / FC1N, j = tid % FC1N;
    const float* w = p.W1 + j * H;
    float a = p.b1[j];
#pragma unroll
    for (int k = 0; k < H; ++k) a += (float)Hb[2][1][b][k] * w[k];
    fc1_buf[b][j] = fmaxf(a, 0.0f);
  }
  __syncthreads();
  if (tid < BPG) {
    float a = p.b2[0];
#pragma unroll
    for (int j = 0; j < FC1N; ++j) a += fc1_buf[tid][j] * p.W2[j];
    p.out[b0 + tid] = a;
  }
}

extern "C" void kernel_launch(void* const* d_in, const int* in_sizes, int n_in,
                              void* d_out, int out_size, void* d_ws, size_t ws_size,
                              hipStream_t stream) {
  Params p;
  p.x = (const float*)d_in[0];
  for (int l = 0; l < NL; ++l) {
    p.Wih[l] = (const float*)d_in[1 + 4 * l];
    p.Whh[l] = (const float*)d_in[2 + 4 * l];
    p.bih[l] = (const float*)d_in[3 + 4 * l];
    p.bhh[l] = (const float*)d_in[4 + 4 * l];
  }
  p.W1 = (const float*)d_in[17];
  p.b1 = (const float*)d_in[18];
  p.W2 = (const float*)d_in[19];
  p.b2 = (const float*)d_in[20];
  p.out = (float*)d_out;

  hipLaunchKernelGGL(lstm_r13, dim3(NBLK), dim3(NTHREADS), 0, stream, p);
}

// Round 6
// 509.865 us; speedup vs baseline: 2.5594x; 1.0981x over previous
//
#include <hip/hip_runtime.h>

// LSTMModel: 4-layer LSTM (H=50, IN=7, B=1024, T=512) + FC(50->25 relu ->1).
// R14 = R10's schedule with the wave partition changed 16 -> 8 FAT waves.
//
// Evidence: R10's 2090cy tick >> all issue budgets (MFMA ~230cy/SIMD, VALU
// ~500cy/SIMD, LDS ~440cy/CU); the residual is latency + convergence: 16
// barrier-locked waves issue 56 b128 LDS reads at once (queue ~440cy before
// the last wave starts), each wave has only 2-4-deep ILP, and the barrier
// waits for the convergence tail. R13 (flag sync) proved software coordination
// costs more than s_barrier; R9/R11/R12 proved added handoffs lose. Untested
// axis: FEWER, FATTER waves -- per-CU issue totals are invariant under the
// re-partition (trans instrs/CU stays exactly 128), so only the latency/
// convergence terms change: rendezvous width 16->8, LDS burst 56->28 b128,
// per-wave ILP 4->7 independent MFMA chains + 2 independent UPD chains.
//
// Partition: wave w=tid>>6 (8 waves): glay=w>>1, half hf=w&1. Half hf owns
// M-chunks [7hf, 7hf + (7-hf)) of 16 gate-rows (13 chunks = 208 >= 200 rows),
// full K=128 (4 kgroups) per wave. Each lane runs TWO gate updates:
// round0 unit u0=(cb0+tsel)*4+quad (always valid), round1 u1=u0+16 (guarded)
// -- R12's proven build/extract index math (build-u uses tsel, extract-u uses
// quad, per A-row=col / C-row=4*quad+reg fragment layouts).
// Everything else verbatim R10: slot schedule skew-1 (515 slots), parity
// read [s&1] write [(s+1)&1], XP packing [x|1.0|h0], Hbuf const-1.0@56,
// Xstage 64-ring + burst refill, exp2 constants folded into weights, setprio
// around MFMA cluster, FC head.

#define H 50
#define INSZ 7
#define TT 512
#define NL 4
#define FC1N 25
#define BPG 4
#define NBLK 256
#define NTHREADS 512
#define HS 80        // row stride in halves (40 dw = 8 mod 32: <=2-way, free)
#define BIASL 56

typedef _Float16 half_t;
typedef __attribute__((ext_vector_type(8))) _Float16 half8_t;
typedef __attribute__((ext_vector_type(4))) float float4_t;

struct Params {
  const float* x;
  const float* Wih[NL];
  const float* Whh[NL];
  const float* bih[NL];
  const float* bhh[NL];
  const float* W1;
  const float* b1;
  const float* W2;
  const float* b2;
  float* out;
};

#define MFMA16(A, B, C) __builtin_amdgcn_mfma_f32_16x16x32_f16((A), (B), (C), 0, 0, 0)
#define EXP2F(x) __builtin_amdgcn_exp2f(x)
#define RCPF(x) __builtin_amdgcn_rcpf(x)

// Gate update: g = pre-scaled (i,f,g,o) pre-acts; c = cell (in/out); h = out.
#define UPD(g, c, h)                                                     \
  const float di = 1.0f + EXP2F((g)[0]);                                 \
  const float df = 1.0f + EXP2F((g)[1]);                                 \
  const float dgg = 1.0f + EXP2F((g)[2]);                                \
  const float dq = 1.0f + EXP2F((g)[3]);                                 \
  const float r1 = RCPF(di * df);                                        \
  const float r2 = RCPF(dgg * dq);                                       \
  const float gi = r1 * df;                                              \
  const float gf = r1 * di;                                              \
  const float gg = 2.0f * (r2 * dq) - 1.0f;                              \
  const float go = r2 * dgg;                                             \
  (c) = gf * (c) + gi * gg;                                              \
  const float dc = 1.0f + EXP2F(-2.885390082f * (c));                    \
  const float h = go * (2.0f * RCPF(dc) - 1.0f);

__global__ __launch_bounds__(NTHREADS, 2) void lstm_r14(Params p) {
  __shared__ __align__(16) half_t XP[2][BPG][HS];        // L0 B-row / L1 input
  __shared__ __align__(16) half_t Hbuf[3][2][BPG][HS];   // own-h L1..L3
  __shared__ __align__(16) half_t Xstage[64][BPG][8];    // raw-x ring
  __shared__ float fc_h[BPG][H];
  __shared__ float fc1_buf[BPG][FC1N];

  const int tid = threadIdx.x;
  const int b0 = blockIdx.x * BPG;
  const int lane = tid & 63;
  const int quad = lane >> 4;
  const int col = lane & 15;
  const int w = tid >> 6;        // 0..7
  const int glay = w >> 1;       // layer
  const int hf = w & 1;          // chunk half: 0 -> chunks 0..6, 1 -> 7..12
  const int cb0 = hf * 7;
  const int bb = col & 3;
  const int tsel = col >> 2;

  // ---- A fragments af[lcc][kg]: chunk cc=cb0+lcc covers gate-rows
  //      r = cc*16 + col (A row = col); u = cc*4 + tsel, q = col&3;
  //      k = kg*32 + quad*8 + j. Pre-scaled by the gate's exp2 constant.
  half8_t af[7][4];
  {
    const int q = col & 3;
#pragma unroll
    for (int lcc = 0; lcc < 7; ++lcc) {
      const int u = (cb0 + lcc) * 4 + tsel;
#pragma unroll
      for (int kg = 0; kg < 4; ++kg) {
        half8_t v;
#pragma unroll
        for (int j = 0; j < 8; ++j) {
          const int k = kg * 32 + quad * 8 + j;
          float wv = 0.0f;
          if (u < H) {
            const int row = q * H + u;
            if (glay == 0) {           // K=64: x 0..6, bias 7, own-h 8..57
              if (k < INSZ) wv = p.Wih[0][row * INSZ + k];
              else if (k == 7) wv = p.bih[0][row] + p.bhh[0][row];
              else if (k >= 8 && k < 8 + H) wv = p.Whh[0][row * H + (k - 8)];
            } else if (glay == 1) {    // input from XP: bias 7, in-h 8..57
              if (k == 7) wv = p.bih[1][row] + p.bhh[1][row];
              else if (k >= 8 && k < 8 + H) wv = p.Wih[1][row * H + (k - 8)];
              else if (k >= 64 && k < 64 + H) wv = p.Whh[1][row * H + (k - 64)];
            } else {                   // in-h 0..49, bias 56, own-h 64..113
              if (k < H) wv = p.Wih[glay][row * H + k];
              else if (k == BIASL) wv = p.bih[glay][row] + p.bhh[glay][row];
              else if (k >= 64 && k < 64 + H) wv = p.Whh[glay][row * H + (k - 64)];
            }
            wv *= (q == 2) ? -2.885390082f : -1.442695041f;  // fold exp2 scale
          }
          v[j] = (half_t)wv;
        }
        af[lcc][kg] = v;
      }
    }
  }

  // ---- init LDS ----
  {
    unsigned* xz = (unsigned*)XP;
    for (int i = tid; i < 2 * BPG * HS / 2; i += NTHREADS) xz[i] = 0u;
    unsigned* hz = (unsigned*)Hbuf;
    for (int i = tid; i < 3 * 2 * BPG * HS / 2; i += NTHREADS) hz[i] = 0u;
  }
  __syncthreads();
  if (tid < 8) {  // XP bias-1.0 at slot 7, both parities
    XP[tid >> 2][tid & 3][7] = (half_t)1.0f;
  } else if (tid < 8 + 24) {  // Hbuf const-1.0 at slot 56
    const int i = tid - 8, l = i >> 3, pr = (i >> 2) & 1, b = i & 3;
    Hbuf[l][pr][b][BIASL] = (half_t)1.0f;
  }
  // ring fill t=0..63 + x(0) into XP[0]
  for (int i = tid; i < 64 * BPG * INSZ; i += NTHREADS) {
    const int t = i / (BPG * INSZ), rem = i % (BPG * INSZ);
    const int b = rem / INSZ, k = rem % INSZ;
    const half_t xh = (half_t)p.x[((size_t)(b0 + b) * TT + t) * INSZ + k];
    Xstage[t][b][k] = xh;
    if (t == 0) XP[0][b][k] = xh;
  }
  __syncthreads();

  // ---- per-lane roles ----
  const int u0c = (cb0 + tsel) * 4 + quad;        // round-0 unit (always <44)
  const int u1c = u0c + 16;                       // round-1 unit
  const bool r1ok = ((4 + tsel) < (7 - hf)) && (u1c < H);

  // phase-hoisted pointers: read [s&1], store [(s+1)&1]. STB = store row base.
  const half_t* pin2[2];
  const half_t* pown2[2];
  half_t* pst2[2];
  if (glay == 0) {
    pin2[0] = &XP[0][bb][quad * 8];
    pin2[1] = &XP[1][bb][quad * 8];
    pown2[0] = pin2[0];  // unused
    pown2[1] = pin2[1];
    pst2[0] = &XP[1][bb][8];
    pst2[1] = &XP[0][bb][8];
  } else if (glay == 1) {
    pin2[0] = &XP[0][bb][quad * 8];
    pin2[1] = &XP[1][bb][quad * 8];
    pown2[0] = &Hbuf[0][0][bb][quad * 8];
    pown2[1] = &Hbuf[0][1][bb][quad * 8];
    pst2[0] = &Hbuf[0][1][bb][0];
    pst2[1] = &Hbuf[0][0][bb][0];
  } else {
    pin2[0] = &Hbuf[glay - 2][0][bb][quad * 8];
    pin2[1] = &Hbuf[glay - 2][1][bb][quad * 8];
    pown2[0] = &Hbuf[glay - 1][0][bb][quad * 8];
    pown2[1] = &Hbuf[glay - 1][1][bb][quad * 8];
    pst2[0] = &Hbuf[glay - 1][1][bb][0];
    pst2[1] = &Hbuf[glay - 1][0][bb][0];
  }
  const half_t* in_e = pin2[0];
  const half_t* in_o = pin2[1];
  const half_t* own_e = pown2[0];
  const half_t* own_o = pown2[1];
  half_t* st_e = pst2[0];
  half_t* st_o = pst2[1];

  // x-copy + ring-refill role: wave 1 (L0 hf1: 12 MFMAs, lightest)
  const bool xwave = (w == 1);
  const bool xcopy = xwave && (lane < BPG * INSZ);
  const int cb = lane / INSZ, ck = lane % INSZ;  // valid when xcopy
  const int rb = lane >> 5;                      // refill: batch pair
  const int rt = lane & 31;                      //         t offset

  float cst0 = 0.0f, cst1 = 0.0f;
  const float4_t fzc = {0.0f, 0.0f, 0.0f, 0.0f};

#define TICK_BODY(PIN, POWN, STB, FCW)                                          \
  {                                                                             \
    const half8_t v0 = *(const half8_t*)(PIN);                                  \
    const half8_t v1 = *(const half8_t*)((PIN) + 32);                           \
    float4_t a0, a1, a2, a3, a4, a5, a6;                                        \
    if (glay == 0) {                                                            \
      __builtin_amdgcn_s_setprio(1);                                            \
      a0 = MFMA16(af[0][0], v0, fzc); a1 = MFMA16(af[1][0], v0, fzc);           \
      a2 = MFMA16(af[2][0], v0, fzc); a3 = MFMA16(af[3][0], v0, fzc);           \
      a4 = MFMA16(af[4][0], v0, fzc); a5 = MFMA16(af[5][0], v0, fzc);           \
      a0 = MFMA16(af[0][1], v1, a0);  a1 = MFMA16(af[1][1], v1, a1);            \
      a2 = MFMA16(af[2][1], v1, a2);  a3 = MFMA16(af[3][1], v1, a3);            \
      a4 = MFMA16(af[4][1], v1, a4);  a5 = MFMA16(af[5][1], v1, a5);            \
      if (hf == 0) {                                                            \
        a6 = MFMA16(af[6][0], v0, fzc);                                         \
        a6 = MFMA16(af[6][1], v1, a6);                                          \
      } else {                                                                  \
        a6 = a5;                                                                \
      }                                                                         \
      __builtin_amdgcn_s_setprio(0);                                            \
    } else {                                                                    \
      const half8_t v2 = *(const half8_t*)(POWN);                               \
      const half8_t v3 = *(const half8_t*)((POWN) + 32);                        \
      __builtin_amdgcn_s_setprio(1);                                            \
      a0 = MFMA16(af[0][0], v0, fzc); a1 = MFMA16(af[1][0], v0, fzc);           \
      a2 = MFMA16(af[2][0], v0, fzc); a3 = MFMA16(af[3][0], v0, fzc);           \
      a4 = MFMA16(af[4][0], v0, fzc); a5 = MFMA16(af[5][0], v0, fzc);           \
      a0 = MFMA16(af[0][1], v1, a0);  a1 = MFMA16(af[1][1], v1, a1);            \
      a2 = MFMA16(af[2][1], v1, a2);  a3 = MFMA16(af[3][1], v1, a3);            \
      a4 = MFMA16(af[4][1], v1, a4);  a5 = MFMA16(af[5][1], v1, a5);            \
      a0 = MFMA16(af[0][2], v2, a0);  a1 = MFMA16(af[1][2], v2, a1);            \
      a2 = MFMA16(af[2][2], v2, a2);  a3 = MFMA16(af[3][2], v2, a3);            \
      a4 = MFMA16(af[4][2], v2, a4);  a5 = MFMA16(af[5][2], v2, a5);            \
      a0 = MFMA16(af[0][3], v3, a0);  a1 = MFMA16(af[1][3], v3, a1);            \
      a2 = MFMA16(af[2][3], v3, a2);  a3 = MFMA16(af[3][3], v3, a3);            \
      a4 = MFMA16(af[4][3], v3, a4);  a5 = MFMA16(af[5][3], v3, a5);            \
      if (hf == 0) {                                                            \
        a6 = MFMA16(af[6][0], v0, fzc);                                         \
        a6 = MFMA16(af[6][1], v1, a6);                                          \
        a6 = MFMA16(af[6][2], v2, a6);                                          \
        a6 = MFMA16(af[6][3], v3, a6);                                          \
      } else {                                                                  \
        a6 = a5;                                                                \
      }                                                                         \
      __builtin_amdgcn_s_setprio(0);                                            \
    }                                                                           \
    /* round 0: chunk lcc = tsel (unit u0c) */                                  \
    const float4_t x01 = (tsel & 1) ? a1 : a0;                                  \
    const float4_t x23 = (tsel & 1) ? a3 : a2;                                  \
    const float4_t o0 = (tsel & 2) ? x23 : x01;                                 \
    {                                                                           \
      UPD(o0, cst0, h0v)                                                        \
      (STB)[u0c] = (half_t)h0v;                                                 \
      if (FCW) fc_h[bb][u0c] = h0v;                                             \
    }                                                                           \
    /* round 1: chunk lcc = 4+tsel (unit u1c), store-guarded */                 \
    const float4_t y45 = (tsel & 1) ? a5 : a4;                                  \
    const float4_t o1 = (tsel & 2) ? a6 : y45;                                  \
    {                                                                           \
      UPD(o1, cst1, h1v)                                                        \
      if (r1ok) {                                                               \
        (STB)[u1c] = (half_t)h1v;                                               \
        if (FCW) fc_h[bb][u1c] = h1v;                                           \
      }                                                                         \
    }                                                                           \
  }

  // x-copy: ring row (s+1) -> XP[(s+1)&1] slots 0..6 (28 lanes of wave 1)
#define XCOPY(S)                                                                \
  if (xcopy) {                                                                  \
    const int tn = (S) + 1;                                                     \
    XP[tn & 1][cb][ck] = Xstage[tn & 63][cb][ck];                               \
  }

  // ---- prologue: s = 0..2 (guarded, dynamic parity) ----
  for (int s = 0; s < 3; ++s) {
    const int t = s - glay;
    if (t >= 0) {
      const int ph = s & 1;
      TICK_BODY(pin2[ph], pown2[ph], pst2[ph], false)
    }
    XCOPY(s)
    __syncthreads();
  }

  // ---- steady: s = 3..510, unrolled x2, compile-time phase ----
  for (int s = 3; s < 511; s += 2) {
    {  // odd tick s (ph=1)
      TICK_BODY(in_o, own_o, st_o, false)
      XCOPY(s)
    }
    __syncthreads();
    {  // even tick s+1 (ph=0)
      const int s2 = s + 1;
      if (xwave && (s2 & 31) == 8 && s2 < 480) {  // ring refill burst
        const int tb = (s2 & ~31) + 32;
#pragma unroll
        for (int pp = 0; pp < 2; ++pp) {
          const int b = rb + 2 * pp;
          const int t = tb + rt;
          const float* src = &p.x[((size_t)(b0 + b) * TT + t) * INSZ];
          half_t* dst = &Xstage[t & 63][b][0];
#pragma unroll
          for (int k = 0; k < INSZ; ++k) dst[k] = (half_t)src[k];
        }
      }
      TICK_BODY(in_e, own_e, st_e, false)
      XCOPY(s2)
    }
    __syncthreads();
  }

  // ---- tail: s = 511..514 (guarded; no x-copy) ----
  for (int s = 511; s < TT + NL - 1; ++s) {
    const int t = s - glay;
    if (t < TT) {
      const int ph = s & 1;
      const bool fcw = (glay == NL - 1) && (t == TT - 1);
      TICK_BODY(pin2[ph], pown2[ph], pst2[ph], fcw)
    }
    __syncthreads();
  }

  // ---- FC head (fp32) ----
  if (tid < BPG * FC1N) {
    const int b = tid / FC1N, j = tid % FC1N;
    const float* wgt = p.W1 + j * H;
    float a = p.b1[j];
#pragma unroll
    for (int k = 0; k < H; ++k) a += fc_h[b][k] * wgt[k];
    fc1_buf[b][j] = fmaxf(a, 0.0f);
  }
  __syncthreads();
  if (tid < BPG) {
    float a = p.b2[0];
#pragma unroll
    for (int j = 0; j < FC1N; ++j) a += fc1_buf[tid][j] * p.W2[j];
    p.out[b0 + tid] = a;
  }
}

extern "C" void kernel_launch(void* const* d_in, const int* in_sizes, int n_in,
                              void* d_out, int out_size, void* d_ws, size_t ws_size,
                              hipStream_t stream) {
  Params p;
  p.x = (const float*)d_in[0];
  for (int l = 0; l < NL; ++l) {
    p.Wih[l] = (const float*)d_in[1 + 4 * l];
    p.Whh[l] = (const float*)d_in[2 + 4 * l];
    p.bih[l] = (const float*)d_in[3 + 4 * l];
    p.bhh[l] = (const float*)d_in[4 + 4 * l];
  }
  p.W1 = (const float*)d_in[17];
  p.b1 = (const float*)d_in[18];
  p.W2 = (const float*)d_in[19];
  p.b2 = (const float*)d_in[20];
  p.out = (float*)d_out;

  hipLaunchKernelGGL(lstm_r14, dim3(NBLK), dim3(NTHREADS), 0, stream, p);
}